// Round 3
// baseline (945.117 us; speedup 1.0000x reference)
//
#include <hip/hip_runtime.h>
#include <hip/hip_bf16.h>

#define NT 8192      // tokens
#define DM 1024      // d_model
#define NE 8         // experts
#define DH 4096      // d_hidden
#define NP (NT * 2)  // token-expert pairs (TOP_K = 2)

typedef __attribute__((ext_vector_type(8))) __bf16 bf16x8;
typedef __attribute__((ext_vector_type(4))) float f32x4;

__device__ __forceinline__ ushort f2bf(float f) {
  unsigned int x = __float_as_uint(f);
  unsigned int r = (x + 0x7fffu + ((x >> 16) & 1u)) >> 16;  // RNE
  return (ushort)r;
}

// exact tanh-gelu, rearranged: 0.5x(1+tanh(z)) = x*e^{2z}/(e^{2z}+1)
__device__ __forceinline__ float gelu_fast(float x) {
  float x2 = x * x;
  float t = __builtin_fmaf(x2, 0.044715f, 1.0f);
  float m = x * t * 2.3025851f;
  m = fminf(m, 126.0f);
  float p = __builtin_amdgcn_exp2f(m);
  return x * p * __builtin_amdgcn_rcpf(p + 1.0f);
}

__device__ __forceinline__ void async_copy16(const void* gsrc, void* ldst) {
  __builtin_amdgcn_global_load_lds(
      (const __attribute__((address_space(1))) void*)gsrc,
      (__attribute__((address_space(3))) void*)ldst, 16, 0, 0);
}

// ------------- fused weight transpose+cvt: w1 [E][DM][DH] -> w1t [E][DH][DM],
//               w2 [E][DH][DM] -> w2t [E][DM][DH]. 64x64 tiles, 256 thr. -------------
__global__ __launch_bounds__(256) void transpose2_kernel(
    const float* __restrict__ w1, const float* __restrict__ w2,
    ushort* __restrict__ w1t, ushort* __restrict__ w2t) {
  const int b = blockIdx.x;
  const int which = b >> 13;         // 0 = w1, 1 = w2
  const int rem = b & 8191;
  const int e = rem >> 10;
  const int t = rem & 1023;          // 1024 tiles of 64x64 per expert-weight
  const float* src;
  ushort* dst;
  int R, C, c0, r0;
  if (which == 0) {
    src = w1 + (size_t)e * DM * DH; dst = w1t + (size_t)e * DM * DH;
    R = DM; C = DH; c0 = (t & 63) * 64; r0 = (t >> 6) * 64;
  } else {
    src = w2 + (size_t)e * DM * DH; dst = w2t + (size_t)e * DM * DH;
    R = DH; C = DM; c0 = (t & 15) * 64; r0 = (t >> 4) * 64;
  }
  __shared__ ushort tileT[64][72];   // [col][row], stride 72
  const int tx = threadIdx.x & 15, ty = threadIdx.x >> 4;  // 16 x 16
#pragma unroll
  for (int i = 0; i < 4; i++) {
    int r = ty + i * 16;
    float4 v = *(const float4*)(src + (size_t)(r0 + r) * C + c0 + tx * 4);
    tileT[tx * 4 + 0][r] = f2bf(v.x);
    tileT[tx * 4 + 1][r] = f2bf(v.y);
    tileT[tx * 4 + 2][r] = f2bf(v.z);
    tileT[tx * 4 + 3][r] = f2bf(v.w);
  }
  __syncthreads();
#pragma unroll
  for (int i = 0; i < 4; i++) {
    int c = ty + i * 16;
    *(ushort4*)(dst + (size_t)(c0 + c) * R + r0 + tx * 4) = *(const ushort4*)(&tileT[c][tx * 4]);
  }
}

// ---------------- gating (+ fused input->bf16): one wave per token ----------------
__global__ void gate_cvt_kernel(const float* __restrict__ inp, const float* __restrict__ gw,
                                const float* __restrict__ gb, ushort* __restrict__ inp_bf,
                                int* __restrict__ counts, int* __restrict__ tok_list,
                                float* __restrict__ scale_list, int* __restrict__ pair_loc) {
  int wave = threadIdx.x >> 6, lane = threadIdx.x & 63;
  int token = blockIdx.x * 4 + wave;
  const float* x = inp + (size_t)token * DM;
  ushort* xb = inp_bf + (size_t)token * DM;
  float acc[NE];
#pragma unroll
  for (int e = 0; e < NE; e++) acc[e] = 0.f;
#pragma unroll
  for (int j = 0; j < 16; j++) {
    int idx = j * 64 + lane;
    float xv = x[idx];
    xb[idx] = f2bf(xv);
    const float4* g = (const float4*)(gw + (size_t)idx * NE);
    float4 g0 = g[0], g1 = g[1];
    acc[0] += xv * g0.x; acc[1] += xv * g0.y; acc[2] += xv * g0.z; acc[3] += xv * g0.w;
    acc[4] += xv * g1.x; acc[5] += xv * g1.y; acc[6] += xv * g1.z; acc[7] += xv * g1.w;
  }
#pragma unroll
  for (int e = 0; e < NE; e++) {
    for (int off = 32; off; off >>= 1) acc[e] += __shfl_xor(acc[e], off, 64);
  }
  if (lane == 0) {
    float v[NE];
#pragma unroll
    for (int e = 0; e < NE; e++) v[e] = acc[e] + gb[e];
    int i0 = 0; float b0 = v[0];
#pragma unroll
    for (int e = 1; e < NE; e++) if (v[e] > b0) { b0 = v[e]; i0 = e; }
    int i1 = -1; float b1v = -INFINITY;
#pragma unroll
    for (int e = 0; e < NE; e++) if (e != i0 && v[e] > b1v) { b1v = v[e]; i1 = e; }
    float s1 = 1.f / (1.f + __expf(b0 - b1v));  // softmax over the two selected logits
    float s0 = 1.f - s1;
    int p0 = atomicAdd(&counts[i0], 1);
    tok_list[i0 * NT + p0] = token;
    scale_list[i0 * NT + p0] = s0;
    pair_loc[token * 2 + 0] = i0 * NT + p0;
    int p1 = atomicAdd(&counts[i1], 1);
    tok_list[i1 * NT + p1] = token;
    scale_list[i1 * NT + p1] = s1;
    pair_loc[token * 2 + 1] = i1 * NT + p1;
  }
}

// 256x256 tile, 512 thr (8 waves = 2M x 4N), per-wave out 128x64 (M_rep 8 x N_rep 4).
// Counted-vmcnt 3-buffer pipeline (T3/T4) + chunk-XOR LDS swizzle (T2, both-sides).
// Buffer = 32 KB: A[256][32]bf16 (16 KB) then B[256][32]bf16 (16 KB); within each
// 64B row the four 16B chunks sit at chunk^((row>>1)&3). 3 buffers = 96 KB -> 1 block/CU.
// Staging: thread t covers rows sr=t>>2 and sr+128, chunk t&3 -> global chunk (t&3)^((sr>>1)&3).
// (row+128 has the same swizzle key since 128>>1 = 64 == 0 mod 4.)
// Each wave issues exactly 4 loads per stage -> vmcnt(4) completes the oldest stage.

#define STAGE_TILE(base)                                       \
  do {                                                         \
    async_copy16(aP0, (char*)(base) + wv * 1024);              \
    async_copy16(aP1, (char*)(base) + 8192 + wv * 1024);       \
    async_copy16(bP0, (char*)(base) + 16384 + wv * 1024);      \
    async_copy16(bP1, (char*)(base) + 24576 + wv * 1024);      \
    aP0 += 32; aP1 += 32; bP0 += 32; bP1 += 32;                \
  } while (0)

// ---------------- GEMM1: h[off_e+gi] = gelu(x[tok] @ w1[e] + b1[e]), bf16 dense ----------------
__global__ __launch_bounds__(512, 2) void gemm1_kernel(
    const ushort* __restrict__ xbf, const ushort* __restrict__ w1t,
    const float* __restrict__ b1, const int* __restrict__ tok_list,
    const int* __restrict__ counts, ushort* __restrict__ hbuf) {
  const int b = blockIdx.x;
  const int e = b & 7;
  const int idx = b >> 3;        // 0..511
  const int mTile = idx & 31;    // fastest: A-panel reuse across nTiles on same XCD
  const int nTile = idx >> 5;    // 0..15
  int off = 0;
  for (int i = 0; i < e; i++) off += counts[i];
  const int cnt = counts[e];
  if (mTile * 256 >= cnt) return;

  __shared__ __attribute__((aligned(128))) char ldsB[98304];  // 3 x (A 16KB + B 16KB)

  const int t = threadIdx.x;
  const int lane = t & 63, wv = t >> 6;
  const int wm = wv >> 2, wn = wv & 3;   // 2M x 4N wave grid

  const int sr = t >> 2;                              // staging row 0..127
  const int sc = (((t & 3) ^ ((sr >> 1) & 3)) * 8);   // swizzled source chunk (ushorts)
  int gi0 = mTile * 256 + sr;       if (gi0 >= cnt) gi0 = cnt - 1;
  int gi1 = mTile * 256 + 128 + sr; if (gi1 >= cnt) gi1 = cnt - 1;
  const int tok0 = tok_list[e * NT + gi0];
  const int tok1 = tok_list[e * NT + gi1];
  const ushort* aP0 = xbf + (size_t)tok0 * DM + sc;
  const ushort* aP1 = xbf + (size_t)tok1 * DM + sc;
  const ushort* bP0 = w1t + ((size_t)e * DH + nTile * 256 + sr) * DM + sc;
  const ushort* bP1 = bP0 + (size_t)128 * DM;

  f32x4 zero = {0.f, 0.f, 0.f, 0.f};
  f32x4 acc[8][4];
#pragma unroll
  for (int i = 0; i < 8; i++)
#pragma unroll
    for (int j = 0; j < 4; j++) acc[i][j] = zero;

  const int quad = lane >> 4, lc = lane & 15;
  const int rq = quad ^ ((lc >> 1) & 3);          // swizzled chunk for reads

  auto compute = [&](const char* buf) {
    const char* A_ = buf;
    const char* B_ = buf + 16384;
    bf16x8 af[8], bfr[4];
#pragma unroll
    for (int mi = 0; mi < 8; mi++) {
      int row = wm * 128 + mi * 16 + lc;
      af[mi] = *(const bf16x8*)(A_ + row * 64 + rq * 16);
    }
#pragma unroll
    for (int ni = 0; ni < 4; ni++) {
      int row = wn * 64 + ni * 16 + lc;
      bfr[ni] = *(const bf16x8*)(B_ + row * 64 + rq * 16);
    }
#pragma unroll
    for (int mi = 0; mi < 8; mi++)
#pragma unroll
      for (int ni = 0; ni < 4; ni++)
        acc[mi][ni] = __builtin_amdgcn_mfma_f32_16x16x32_bf16(af[mi], bfr[ni], acc[mi][ni], 0, 0, 0);
  };

  const int NIT = DM / 32;  // 32
  STAGE_TILE(ldsB);
  STAGE_TILE(ldsB + 32768);
  int cur = 0;
  for (int tt = 0; tt < NIT - 1; ++tt) {
    // outstanding = stage(tt)+stage(tt+1) = 8; complete the oldest 4 = stage(tt)
    asm volatile("s_waitcnt vmcnt(4)" ::: "memory");
    __builtin_amdgcn_s_barrier();   // buf(tt) fully staged; all waves done reading buf(tt-1)
    if (tt + 2 < NIT) {
      int nx = cur + 2; if (nx >= 3) nx -= 3;
      STAGE_TILE(ldsB + nx * 32768);
    }
    compute(ldsB + cur * 32768);
    cur = (cur == 2) ? 0 : cur + 1;
  }
  asm volatile("s_waitcnt vmcnt(0)" ::: "memory");
  __builtin_amdgcn_s_barrier();
  compute(ldsB + cur * 32768);

  float bias[4];
#pragma unroll
  for (int ni = 0; ni < 4; ni++)
    bias[ni] = b1[(size_t)e * DH + nTile * 256 + wn * 64 + ni * 16 + lc];

#pragma unroll
  for (int mi = 0; mi < 8; mi++) {
#pragma unroll
    for (int r = 0; r < 4; r++) {
      int lr = wm * 128 + mi * 16 + quad * 4 + r;
      int gi = mTile * 256 + lr;
      if (gi < cnt) {
        ushort* hrow = hbuf + (size_t)(off + gi) * DH + nTile * 256 + wn * 64 + lc;
#pragma unroll
        for (int ni = 0; ni < 4; ni++) {
          float v = acc[mi][ni][r] + bias[ni];
          hrow[ni * 16] = f2bf(gelu_fast(v));
        }
      }
    }
  }
}

// ---------------- GEMM2: pbuf[off_e+gi] = h @ w2[e] + b2[e] (unscaled, plain stores) ----------------
__global__ __launch_bounds__(512, 2) void gemm2_kernel(
    const ushort* __restrict__ hbuf, const ushort* __restrict__ w2t,
    const float* __restrict__ b2, const int* __restrict__ counts,
    float* __restrict__ pbuf) {
  const int b = blockIdx.x;
  const int e = b & 7;               // XCD pin
  const int idx = b >> 3;            // 0..127
  const int nTile = idx & 3;         // fastest: hbuf A-panel reuse
  const int mTile = idx >> 2;        // 0..31
  int off = 0;
  for (int i = 0; i < e; i++) off += counts[i];
  const int cnt = counts[e];
  if (mTile * 256 >= cnt) return;

  __shared__ __attribute__((aligned(128))) char ldsB[98304];  // 3 x (A 16KB + B 16KB)

  const int t = threadIdx.x;
  const int lane = t & 63, wv = t >> 6;
  const int wm = wv >> 2, wn = wv & 3;

  const int sr = t >> 2;
  const int sc = (((t & 3) ^ ((sr >> 1) & 3)) * 8);
  int gi0 = mTile * 256 + sr;       if (gi0 >= cnt) gi0 = cnt - 1;
  int gi1 = mTile * 256 + 128 + sr; if (gi1 >= cnt) gi1 = cnt - 1;
  const ushort* aP0 = hbuf + (size_t)(off + gi0) * DH + sc;
  const ushort* aP1 = hbuf + (size_t)(off + gi1) * DH + sc;
  const ushort* bP0 = w2t + ((size_t)e * DM + nTile * 256 + sr) * DH + sc;
  const ushort* bP1 = bP0 + (size_t)128 * DH;

  f32x4 zero = {0.f, 0.f, 0.f, 0.f};
  f32x4 acc[8][4];
#pragma unroll
  for (int i = 0; i < 8; i++)
#pragma unroll
    for (int j = 0; j < 4; j++) acc[i][j] = zero;

  const int quad = lane >> 4, lc = lane & 15;
  const int rq = quad ^ ((lc >> 1) & 3);

  auto compute = [&](const char* buf) {
    const char* A_ = buf;
    const char* B_ = buf + 16384;
    bf16x8 af[8], bfr[4];
#pragma unroll
    for (int mi = 0; mi < 8; mi++) {
      int row = wm * 128 + mi * 16 + lc;
      af[mi] = *(const bf16x8*)(A_ + row * 64 + rq * 16);
    }
#pragma unroll
    for (int ni = 0; ni < 4; ni++) {
      int row = wn * 64 + ni * 16 + lc;
      bfr[ni] = *(const bf16x8*)(B_ + row * 64 + rq * 16);
    }
#pragma unroll
    for (int mi = 0; mi < 8; mi++)
#pragma unroll
      for (int ni = 0; ni < 4; ni++)
        acc[mi][ni] = __builtin_amdgcn_mfma_f32_16x16x32_bf16(af[mi], bfr[ni], acc[mi][ni], 0, 0, 0);
  };

  const int NIT = DH / 32;  // 128
  STAGE_TILE(ldsB);
  STAGE_TILE(ldsB + 32768);
  int cur = 0;
  for (int tt = 0; tt < NIT - 1; ++tt) {
    asm volatile("s_waitcnt vmcnt(4)" ::: "memory");
    __builtin_amdgcn_s_barrier();
    if (tt + 2 < NIT) {
      int nx = cur + 2; if (nx >= 3) nx -= 3;
      STAGE_TILE(ldsB + nx * 32768);
    }
    compute(ldsB + cur * 32768);
    cur = (cur == 2) ? 0 : cur + 1;
  }
  asm volatile("s_waitcnt vmcnt(0)" ::: "memory");
  __builtin_amdgcn_s_barrier();
  compute(ldsB + cur * 32768);

  float bias[4];
#pragma unroll
  for (int ni = 0; ni < 4; ni++)
    bias[ni] = b2[(size_t)e * DM + nTile * 256 + wn * 64 + ni * 16 + lc];

#pragma unroll
  for (int mi = 0; mi < 8; mi++) {
#pragma unroll
    for (int r = 0; r < 4; r++) {
      int lr = wm * 128 + mi * 16 + quad * 4 + r;
      int gi = mTile * 256 + lr;
      if (gi < cnt) {
        float* prow = pbuf + (size_t)(off + gi) * DM + nTile * 256 + wn * 64 + lc;
#pragma unroll
        for (int ni = 0; ni < 4; ni++)
          prow[ni * 16] = acc[mi][ni][r] + bias[ni];
      }
    }
  }
}

// ---------------- combine: y[t] = s0*pbuf[row(t,0)] + s1*pbuf[row(t,1)] ----------------
__global__ __launch_bounds__(256) void combine_kernel(
    const float* __restrict__ pbuf, const int* __restrict__ pair_loc,
    const float* __restrict__ scale_list, const int* __restrict__ counts,
    float* __restrict__ y) {
  const int wave = threadIdx.x >> 6, lane = threadIdx.x & 63;
  const int tk = blockIdx.x * 4 + wave;
  const int loc0 = pair_loc[tk * 2 + 0];
  const int loc1 = pair_loc[tk * 2 + 1];
  const float s0 = scale_list[loc0];
  const float s1 = scale_list[loc1];
  const int e0 = loc0 >> 13, p0 = loc0 & (NT - 1);
  const int e1 = loc1 >> 13, p1 = loc1 & (NT - 1);
  int r0 = p0, r1 = p1;
#pragma unroll
  for (int i = 0; i < NE; i++) {
    int c = counts[i];
    if (i < e0) r0 += c;
    if (i < e1) r1 += c;
  }
  const float4* a = (const float4*)(pbuf + (size_t)r0 * DM) + lane;
  const float4* bq = (const float4*)(pbuf + (size_t)r1 * DM) + lane;
  float4* yo = (float4*)(y + (size_t)tk * DM) + lane;
#pragma unroll
  for (int j = 0; j < 4; j++) {
    float4 av = a[j * 64], bv = bq[j * 64];
    float4 o;
    o.x = s0 * av.x + s1 * bv.x;
    o.y = s0 * av.y + s1 * bv.y;
    o.z = s0 * av.z + s1 * bv.z;
    o.w = s0 * av.w + s1 * bv.w;
    yo[j * 64] = o;
  }
}

extern "C" void kernel_launch(void* const* d_in, const int* in_sizes, int n_in,
                              void* d_out, int out_size, void* d_ws, size_t ws_size,
                              hipStream_t stream) {
  const float* inp = (const float*)d_in[0];
  const float* gw  = (const float*)d_in[1];
  const float* gb  = (const float*)d_in[2];
  const float* w1  = (const float*)d_in[3];
  const float* b1  = (const float*)d_in[4];
  const float* w2  = (const float*)d_in[5];
  const float* b2  = (const float*)d_in[6];
  float* y = (float*)d_out;

  // workspace layout (~286 MB total)
  char* ws = (char*)d_ws;
  ushort* inp_bf = (ushort*)ws;              ws += (size_t)NT * DM * 2;
  ushort* w1t    = (ushort*)ws;              ws += (size_t)NE * DH * DM * 2;
  ushort* w2t    = (ushort*)ws;              ws += (size_t)NE * DM * DH * 2;
  ushort* hbuf   = (ushort*)ws;              ws += (size_t)NP * DH * 2;
  int*    tok_list   = (int*)ws;             ws += (size_t)NE * NT * 4;
  float*  scale_list = (float*)ws;           ws += (size_t)NE * NT * 4;
  int*    counts     = (int*)ws;             ws += 256;
  int*    pair_loc   = (int*)ws;             ws += (size_t)NT * 2 * 4;

  // pbuf [NP][DM] fp32 aliases w1t (exactly 64 MiB each): w1t dead after gemm1.
  float* pbuf = (float*)w1t;

  hipMemsetAsync(counts, 0, 256, stream);

  transpose2_kernel<<<2 * NE * 1024, 256, 0, stream>>>(w1, w2, w1t, w2t);
  gate_cvt_kernel<<<NT / 4, 256, 0, stream>>>(inp, gw, gb, inp_bf, counts, tok_list, scale_list, pair_loc);
  // 1D swizzled grids: XCD = linear%8 = expert; grids cover worst-case cnt=NT, excess blocks exit early
  gemm1_kernel<<<NE * 32 * 16, 512, 0, stream>>>(inp_bf, w1t, b1, tok_list, counts, hbuf);
  gemm2_kernel<<<NE * 32 * 4, 512, 0, stream>>>(hbuf, w2t, b2, counts, pbuf);
  combine_kernel<<<NT / 4, 256, 0, stream>>>(pbuf, pair_loc, scale_list, counts, y);
}

// Round 4
// 936.118 us; speedup vs baseline: 1.0096x; 1.0096x over previous
//
#include <hip/hip_runtime.h>
#include <hip/hip_bf16.h>

#define NT 8192      // tokens
#define DM 1024      // d_model
#define NE 8         // experts
#define DH 4096      // d_hidden
#define NP (NT * 2)  // token-expert pairs (TOP_K = 2)

typedef __attribute__((ext_vector_type(8))) __bf16 bf16x8;
typedef __attribute__((ext_vector_type(4))) float f32x4;

__device__ __forceinline__ ushort f2bf(float f) {
  unsigned int x = __float_as_uint(f);
  unsigned int r = (x + 0x7fffu + ((x >> 16) & 1u)) >> 16;  // RNE
  return (ushort)r;
}

// exact tanh-gelu, rearranged: 0.5x(1+tanh(z)) = x*e^{2z}/(e^{2z}+1)
__device__ __forceinline__ float gelu_fast(float x) {
  float x2 = x * x;
  float t = __builtin_fmaf(x2, 0.044715f, 1.0f);
  float m = x * t * 2.3025851f;
  m = fminf(m, 126.0f);
  float p = __builtin_amdgcn_exp2f(m);
  return x * p * __builtin_amdgcn_rcpf(p + 1.0f);
}

__device__ __forceinline__ void async_copy16(const void* gsrc, void* ldst) {
  __builtin_amdgcn_global_load_lds(
      (const __attribute__((address_space(1))) void*)gsrc,
      (__attribute__((address_space(3))) void*)ldst, 16, 0, 0);
}

// ------------- fused weight transpose+cvt: w1 [E][DM][DH] -> w1t [E][DH][DM],
//               w2 [E][DH][DM] -> w2t [E][DM][DH]. 64x64 tiles, 256 thr. -------------
__global__ __launch_bounds__(256) void transpose2_kernel(
    const float* __restrict__ w1, const float* __restrict__ w2,
    ushort* __restrict__ w1t, ushort* __restrict__ w2t) {
  const int b = blockIdx.x;
  const int which = b >> 13;         // 0 = w1, 1 = w2
  const int rem = b & 8191;
  const int e = rem >> 10;
  const int t = rem & 1023;          // 1024 tiles of 64x64 per expert-weight
  const float* src;
  ushort* dst;
  int R, C, c0, r0;
  if (which == 0) {
    src = w1 + (size_t)e * DM * DH; dst = w1t + (size_t)e * DM * DH;
    R = DM; C = DH; c0 = (t & 63) * 64; r0 = (t >> 6) * 64;
  } else {
    src = w2 + (size_t)e * DM * DH; dst = w2t + (size_t)e * DM * DH;
    R = DH; C = DM; c0 = (t & 15) * 64; r0 = (t >> 4) * 64;
  }
  __shared__ ushort tileT[64][72];   // [col][row], stride 72
  const int tx = threadIdx.x & 15, ty = threadIdx.x >> 4;  // 16 x 16
#pragma unroll
  for (int i = 0; i < 4; i++) {
    int r = ty + i * 16;
    float4 v = *(const float4*)(src + (size_t)(r0 + r) * C + c0 + tx * 4);
    tileT[tx * 4 + 0][r] = f2bf(v.x);
    tileT[tx * 4 + 1][r] = f2bf(v.y);
    tileT[tx * 4 + 2][r] = f2bf(v.z);
    tileT[tx * 4 + 3][r] = f2bf(v.w);
  }
  __syncthreads();
#pragma unroll
  for (int i = 0; i < 4; i++) {
    int c = ty + i * 16;
    *(ushort4*)(dst + (size_t)(c0 + c) * R + r0 + tx * 4) = *(const ushort4*)(&tileT[c][tx * 4]);
  }
}

// ---------------- gating (+ fused input->bf16): one wave per token ----------------
__global__ void gate_cvt_kernel(const float* __restrict__ inp, const float* __restrict__ gw,
                                const float* __restrict__ gb, ushort* __restrict__ inp_bf,
                                int* __restrict__ counts, int* __restrict__ tok_list,
                                float* __restrict__ scale_list, int* __restrict__ pair_loc) {
  int wave = threadIdx.x >> 6, lane = threadIdx.x & 63;
  int token = blockIdx.x * 4 + wave;
  const float* x = inp + (size_t)token * DM;
  ushort* xb = inp_bf + (size_t)token * DM;
  float acc[NE];
#pragma unroll
  for (int e = 0; e < NE; e++) acc[e] = 0.f;
#pragma unroll
  for (int j = 0; j < 16; j++) {
    int idx = j * 64 + lane;
    float xv = x[idx];
    xb[idx] = f2bf(xv);
    const float4* g = (const float4*)(gw + (size_t)idx * NE);
    float4 g0 = g[0], g1 = g[1];
    acc[0] += xv * g0.x; acc[1] += xv * g0.y; acc[2] += xv * g0.z; acc[3] += xv * g0.w;
    acc[4] += xv * g1.x; acc[5] += xv * g1.y; acc[6] += xv * g1.z; acc[7] += xv * g1.w;
  }
#pragma unroll
  for (int e = 0; e < NE; e++) {
    for (int off = 32; off; off >>= 1) acc[e] += __shfl_xor(acc[e], off, 64);
  }
  if (lane == 0) {
    float v[NE];
#pragma unroll
    for (int e = 0; e < NE; e++) v[e] = acc[e] + gb[e];
    int i0 = 0; float b0 = v[0];
#pragma unroll
    for (int e = 1; e < NE; e++) if (v[e] > b0) { b0 = v[e]; i0 = e; }
    int i1 = -1; float b1v = -INFINITY;
#pragma unroll
    for (int e = 0; e < NE; e++) if (e != i0 && v[e] > b1v) { b1v = v[e]; i1 = e; }
    float s1 = 1.f / (1.f + __expf(b0 - b1v));  // softmax over the two selected logits
    float s0 = 1.f - s1;
    int p0 = atomicAdd(&counts[i0], 1);
    tok_list[i0 * NT + p0] = token;
    scale_list[i0 * NT + p0] = s0;
    pair_loc[token * 2 + 0] = i0 * NT + p0;
    int p1 = atomicAdd(&counts[i1], 1);
    tok_list[i1 * NT + p1] = token;
    scale_list[i1 * NT + p1] = s1;
    pair_loc[token * 2 + 1] = i1 * NT + p1;
  }
}

// 256x256 tile, 512 thr (8 waves = 2M x 4N), per-wave out 128x64 (M_rep 8 x N_rep 4).
// Counted-vmcnt 3-buffer pipeline (T3/T4) + chunk-XOR LDS swizzle (T2, both-sides)
// + per-K-step TWO-PHASE interleave with setprio (m201 phase granularity: 16 MFMA/phase).
// Buffer = 32 KB: A[256][32]bf16 then B[256][32]bf16; within each 64B row the four
// 16B chunks sit at chunk^((row>>1)&3). 3 buffers = 96 KB -> 1 block/CU, 8 waves.
// Each wave issues exactly 4 stage loads per K-step (2 in P0, 2 in P1) -> vmcnt(4)
// at top of step completes the oldest stage (identical accounting to verified r2/r3).

#define STAGE_TILE(base)                                       \
  do {                                                         \
    async_copy16(aP0, (char*)(base) + wv * 1024);              \
    async_copy16(aP1, (char*)(base) + 8192 + wv * 1024);       \
    async_copy16(bP0, (char*)(base) + 16384 + wv * 1024);      \
    async_copy16(bP1, (char*)(base) + 24576 + wv * 1024);      \
    aP0 += 32; aP1 += 32; bP0 += 32; bP1 += 32;                \
  } while (0)

// Phased K-step body shared by both GEMMs (expanded as a macro over local vars).
#define KSTEP_PHASED(buf, doStage, stageBase)                                         \
  do {                                                                                \
    const char* A_ = (buf);                                                           \
    const char* B_ = (buf) + 16384;                                                   \
    bf16x8 af0[4], af1[4], bfr[4];                                                    \
    _Pragma("unroll")                                                                 \
    for (int mi = 0; mi < 4; mi++)                                                    \
      af0[mi] = *(const bf16x8*)(A_ + (wm * 128 + mi * 16 + lc) * 64 + rq * 16);      \
    _Pragma("unroll")                                                                 \
    for (int ni = 0; ni < 4; ni++)                                                    \
      bfr[ni] = *(const bf16x8*)(B_ + (wn * 64 + ni * 16 + lc) * 64 + rq * 16);       \
    if (doStage) {                                                                    \
      async_copy16(aP0, (char*)(stageBase) + wv * 1024);                              \
      async_copy16(aP1, (char*)(stageBase) + 8192 + wv * 1024);                       \
    }                                                                                 \
    asm volatile("s_waitcnt lgkmcnt(0)" ::: "memory");                                \
    __builtin_amdgcn_sched_barrier(0);                                                \
    __builtin_amdgcn_s_setprio(1);                                                    \
    _Pragma("unroll")                                                                 \
    for (int mi = 0; mi < 4; mi++)                                                    \
      _Pragma("unroll")                                                               \
      for (int ni = 0; ni < 4; ni++)                                                  \
        acc[mi][ni] = __builtin_amdgcn_mfma_f32_16x16x32_bf16(af0[mi], bfr[ni],       \
                                                              acc[mi][ni], 0, 0, 0); \
    __builtin_amdgcn_s_setprio(0);                                                    \
    __builtin_amdgcn_s_barrier();                                                     \
    _Pragma("unroll")                                                                 \
    for (int mi = 0; mi < 4; mi++)                                                    \
      af1[mi] = *(const bf16x8*)(A_ + (wm * 128 + (mi + 4) * 16 + lc) * 64 + rq * 16);\
    if (doStage) {                                                                    \
      async_copy16(bP0, (char*)(stageBase) + 16384 + wv * 1024);                      \
      async_copy16(bP1, (char*)(stageBase) + 24576 + wv * 1024);                      \
      aP0 += 32; aP1 += 32; bP0 += 32; bP1 += 32;                                     \
    }                                                                                 \
    asm volatile("s_waitcnt lgkmcnt(0)" ::: "memory");                                \
    __builtin_amdgcn_sched_barrier(0);                                                \
    __builtin_amdgcn_s_setprio(1);                                                    \
    _Pragma("unroll")                                                                 \
    for (int mi = 0; mi < 4; mi++)                                                    \
      _Pragma("unroll")                                                               \
      for (int ni = 0; ni < 4; ni++)                                                  \
        acc[mi + 4][ni] = __builtin_amdgcn_mfma_f32_16x16x32_bf16(af1[mi], bfr[ni],   \
                                                                  acc[mi + 4][ni],   \
                                                                  0, 0, 0);          \
    __builtin_amdgcn_s_setprio(0);                                                    \
  } while (0)

// ---------------- GEMM1: h[off_e+gi] = gelu(x[tok] @ w1[e] + b1[e]), bf16 dense ----------------
__global__ __launch_bounds__(512, 2) void gemm1_kernel(
    const ushort* __restrict__ xbf, const ushort* __restrict__ w1t,
    const float* __restrict__ b1, const int* __restrict__ tok_list,
    const int* __restrict__ counts, ushort* __restrict__ hbuf) {
  const int b = blockIdx.x;
  const int e = b & 7;
  const int idx = b >> 3;        // 0..511
  const int mTile = idx & 31;    // fastest: A-panel reuse across nTiles on same XCD
  const int nTile = idx >> 5;    // 0..15
  int off = 0;
  for (int i = 0; i < e; i++) off += counts[i];
  const int cnt = counts[e];
  if (mTile * 256 >= cnt) return;

  __shared__ __attribute__((aligned(128))) char ldsB[98304];  // 3 x (A 16KB + B 16KB)

  const int t = threadIdx.x;
  const int lane = t & 63, wv = t >> 6;
  const int wm = wv >> 2, wn = wv & 3;   // 2M x 4N wave grid

  const int sr = t >> 2;                              // staging row 0..127
  const int sc = (((t & 3) ^ ((sr >> 1) & 3)) * 8);   // swizzled source chunk (ushorts)
  int gi0 = mTile * 256 + sr;       if (gi0 >= cnt) gi0 = cnt - 1;
  int gi1 = mTile * 256 + 128 + sr; if (gi1 >= cnt) gi1 = cnt - 1;
  const int tok0 = tok_list[e * NT + gi0];
  const int tok1 = tok_list[e * NT + gi1];
  const ushort* aP0 = xbf + (size_t)tok0 * DM + sc;
  const ushort* aP1 = xbf + (size_t)tok1 * DM + sc;
  const ushort* bP0 = w1t + ((size_t)e * DH + nTile * 256 + sr) * DM + sc;
  const ushort* bP1 = bP0 + (size_t)128 * DM;

  f32x4 zero = {0.f, 0.f, 0.f, 0.f};
  f32x4 acc[8][4];
#pragma unroll
  for (int i = 0; i < 8; i++)
#pragma unroll
    for (int j = 0; j < 4; j++) acc[i][j] = zero;

  const int quad = lane >> 4, lc = lane & 15;
  const int rq = quad ^ ((lc >> 1) & 3);          // swizzled chunk for reads

  const int NIT = DM / 32;  // 32
  STAGE_TILE(ldsB);
  STAGE_TILE(ldsB + 32768);
  int cur = 0;
  for (int tt = 0; tt < NIT - 1; ++tt) {
    // outstanding = stage(tt)+stage(tt+1) = 8; complete the oldest 4 = stage(tt)
    asm volatile("s_waitcnt vmcnt(4)" ::: "memory");
    __builtin_amdgcn_s_barrier();   // buf(tt) fully staged; all waves done reading buf(tt-1)
    {
      int nx = cur + 2; if (nx >= 3) nx -= 3;
      bool doStage = (tt + 2 < NIT);
      KSTEP_PHASED(ldsB + cur * 32768, doStage, ldsB + nx * 32768);
    }
    cur = (cur == 2) ? 0 : cur + 1;
  }
  asm volatile("s_waitcnt vmcnt(0)" ::: "memory");
  __builtin_amdgcn_s_barrier();
  KSTEP_PHASED(ldsB + cur * 32768, false, ldsB);

  float bias[4];
#pragma unroll
  for (int ni = 0; ni < 4; ni++)
    bias[ni] = b1[(size_t)e * DH + nTile * 256 + wn * 64 + ni * 16 + lc];

#pragma unroll
  for (int mi = 0; mi < 8; mi++) {
#pragma unroll
    for (int r = 0; r < 4; r++) {
      int lr = wm * 128 + mi * 16 + quad * 4 + r;
      int gi = mTile * 256 + lr;
      if (gi < cnt) {
        ushort* hrow = hbuf + (size_t)(off + gi) * DH + nTile * 256 + wn * 64 + lc;
#pragma unroll
        for (int ni = 0; ni < 4; ni++) {
          float v = acc[mi][ni][r] + bias[ni];
          hrow[ni * 16] = f2bf(gelu_fast(v));
        }
      }
    }
  }
}

// ---------------- GEMM2: pbuf[off_e+gi] = h @ w2[e] + b2[e] (unscaled, plain stores) ----------------
__global__ __launch_bounds__(512, 2) void gemm2_kernel(
    const ushort* __restrict__ hbuf, const ushort* __restrict__ w2t,
    const float* __restrict__ b2, const int* __restrict__ counts,
    float* __restrict__ pbuf) {
  const int b = blockIdx.x;
  const int e = b & 7;               // XCD pin
  const int idx = b >> 3;            // 0..127
  const int nTile = idx & 3;         // fastest: hbuf A-panel reuse
  const int mTile = idx >> 2;        // 0..31
  int off = 0;
  for (int i = 0; i < e; i++) off += counts[i];
  const int cnt = counts[e];
  if (mTile * 256 >= cnt) return;

  __shared__ __attribute__((aligned(128))) char ldsB[98304];  // 3 x (A 16KB + B 16KB)

  const int t = threadIdx.x;
  const int lane = t & 63, wv = t >> 6;
  const int wm = wv >> 2, wn = wv & 3;

  const int sr = t >> 2;
  const int sc = (((t & 3) ^ ((sr >> 1) & 3)) * 8);
  int gi0 = mTile * 256 + sr;       if (gi0 >= cnt) gi0 = cnt - 1;
  int gi1 = mTile * 256 + 128 + sr; if (gi1 >= cnt) gi1 = cnt - 1;
  const ushort* aP0 = hbuf + (size_t)(off + gi0) * DH + sc;
  const ushort* aP1 = hbuf + (size_t)(off + gi1) * DH + sc;
  const ushort* bP0 = w2t + ((size_t)e * DM + nTile * 256 + sr) * DH + sc;
  const ushort* bP1 = bP0 + (size_t)128 * DH;

  f32x4 zero = {0.f, 0.f, 0.f, 0.f};
  f32x4 acc[8][4];
#pragma unroll
  for (int i = 0; i < 8; i++)
#pragma unroll
    for (int j = 0; j < 4; j++) acc[i][j] = zero;

  const int quad = lane >> 4, lc = lane & 15;
  const int rq = quad ^ ((lc >> 1) & 3);

  const int NIT = DH / 32;  // 128
  STAGE_TILE(ldsB);
  STAGE_TILE(ldsB + 32768);
  int cur = 0;
  for (int tt = 0; tt < NIT - 1; ++tt) {
    asm volatile("s_waitcnt vmcnt(4)" ::: "memory");
    __builtin_amdgcn_s_barrier();
    {
      int nx = cur + 2; if (nx >= 3) nx -= 3;
      bool doStage = (tt + 2 < NIT);
      KSTEP_PHASED(ldsB + cur * 32768, doStage, ldsB + nx * 32768);
    }
    cur = (cur == 2) ? 0 : cur + 1;
  }
  asm volatile("s_waitcnt vmcnt(0)" ::: "memory");
  __builtin_amdgcn_s_barrier();
  KSTEP_PHASED(ldsB + cur * 32768, false, ldsB);

  float bias[4];
#pragma unroll
  for (int ni = 0; ni < 4; ni++)
    bias[ni] = b2[(size_t)e * DM + nTile * 256 + wn * 64 + ni * 16 + lc];

#pragma unroll
  for (int mi = 0; mi < 8; mi++) {
#pragma unroll
    for (int r = 0; r < 4; r++) {
      int lr = wm * 128 + mi * 16 + quad * 4 + r;
      int gi = mTile * 256 + lr;
      if (gi < cnt) {
        float* prow = pbuf + (size_t)(off + gi) * DM + nTile * 256 + wn * 64 + lc;
#pragma unroll
        for (int ni = 0; ni < 4; ni++)
          prow[ni * 16] = acc[mi][ni][r] + bias[ni];
      }
    }
  }
}

// ---------------- combine: y[t] = s0*pbuf[row(t,0)] + s1*pbuf[row(t,1)] ----------------
__global__ __launch_bounds__(256) void combine_kernel(
    const float* __restrict__ pbuf, const int* __restrict__ pair_loc,
    const float* __restrict__ scale_list, const int* __restrict__ counts,
    float* __restrict__ y) {
  const int wave = threadIdx.x >> 6, lane = threadIdx.x & 63;
  const int tk = blockIdx.x * 4 + wave;
  const int loc0 = pair_loc[tk * 2 + 0];
  const int loc1 = pair_loc[tk * 2 + 1];
  const float s0 = scale_list[loc0];
  const float s1 = scale_list[loc1];
  const int e0 = loc0 >> 13, p0 = loc0 & (NT - 1);
  const int e1 = loc1 >> 13, p1 = loc1 & (NT - 1);
  int r0 = p0, r1 = p1;
#pragma unroll
  for (int i = 0; i < NE; i++) {
    int c = counts[i];
    if (i < e0) r0 += c;
    if (i < e1) r1 += c;
  }
  const float4* a = (const float4*)(pbuf + (size_t)r0 * DM) + lane;
  const float4* bq = (const float4*)(pbuf + (size_t)r1 * DM) + lane;
  float4* yo = (float4*)(y + (size_t)tk * DM) + lane;
#pragma unroll
  for (int j = 0; j < 4; j++) {
    float4 av = a[j * 64], bv = bq[j * 64];
    float4 o;
    o.x = s0 * av.x + s1 * bv.x;
    o.y = s0 * av.y + s1 * bv.y;
    o.z = s0 * av.z + s1 * bv.z;
    o.w = s0 * av.w + s1 * bv.w;
    yo[j * 64] = o;
  }
}

extern "C" void kernel_launch(void* const* d_in, const int* in_sizes, int n_in,
                              void* d_out, int out_size, void* d_ws, size_t ws_size,
                              hipStream_t stream) {
  const float* inp = (const float*)d_in[0];
  const float* gw  = (const float*)d_in[1];
  const float* gb  = (const float*)d_in[2];
  const float* w1  = (const float*)d_in[3];
  const float* b1  = (const float*)d_in[4];
  const float* w2  = (const float*)d_in[5];
  const float* b2  = (const float*)d_in[6];
  float* y = (float*)d_out;

  // workspace layout (~286 MB total)
  char* ws = (char*)d_ws;
  ushort* inp_bf = (ushort*)ws;              ws += (size_t)NT * DM * 2;
  ushort* w1t    = (ushort*)ws;              ws += (size_t)NE * DH * DM * 2;
  ushort* w2t    = (ushort*)ws;              ws += (size_t)NE * DM * DH * 2;
  ushort* hbuf   = (ushort*)ws;              ws += (size_t)NP * DH * 2;
  int*    tok_list   = (int*)ws;             ws += (size_t)NE * NT * 4;
  float*  scale_list = (float*)ws;           ws += (size_t)NE * NT * 4;
  int*    counts     = (int*)ws;             ws += 256;
  int*    pair_loc   = (int*)ws;             ws += (size_t)NT * 2 * 4;

  // pbuf [NP][DM] fp32 aliases w1t (exactly 64 MiB each): w1t dead after gemm1.
  float* pbuf = (float*)w1t;

  hipMemsetAsync(counts, 0, 256, stream);

  transpose2_kernel<<<2 * NE * 1024, 256, 0, stream>>>(w1, w2, w1t, w2t);
  gate_cvt_kernel<<<NT / 4, 256, 0, stream>>>(inp, gw, gb, inp_bf, counts, tok_list, scale_list, pair_loc);
  // 1D swizzled grids: XCD = linear%8 = expert; grids cover worst-case cnt=NT, excess blocks exit early
  gemm1_kernel<<<NE * 32 * 16, 512, 0, stream>>>(inp_bf, w1t, b1, tok_list, counts, hbuf);
  gemm2_kernel<<<NE * 32 * 4, 512, 0, stream>>>(hbuf, w2t, b2, counts, pbuf);
  combine_kernel<<<NT / 4, 256, 0, stream>>>(pbuf, pair_loc, scale_list, counts, y);
}

// Round 5
// 905.579 us; speedup vs baseline: 1.0437x; 1.0337x over previous
//
#include <hip/hip_runtime.h>
#include <hip/hip_bf16.h>

#define NT 8192      // tokens
#define DM 1024      // d_model
#define NE 8         // experts
#define DH 4096      // d_hidden
#define NP (NT * 2)  // token-expert pairs (TOP_K = 2)

typedef __attribute__((ext_vector_type(8))) __bf16 bf16x8;
typedef __attribute__((ext_vector_type(4))) float f32x4;

__device__ __forceinline__ ushort f2bf(float f) {
  unsigned int x = __float_as_uint(f);
  unsigned int r = (x + 0x7fffu + ((x >> 16) & 1u)) >> 16;  // RNE
  return (ushort)r;
}

// exact tanh-gelu, rearranged: 0.5x(1+tanh(z)) = x*e^{2z}/(e^{2z}+1)
__device__ __forceinline__ float gelu_fast(float x) {
  float x2 = x * x;
  float t = __builtin_fmaf(x2, 0.044715f, 1.0f);
  float m = x * t * 2.3025851f;
  m = fminf(m, 126.0f);
  float p = __builtin_amdgcn_exp2f(m);
  return x * p * __builtin_amdgcn_rcpf(p + 1.0f);
}

__device__ __forceinline__ void async_copy16(const void* gsrc, void* ldst) {
  __builtin_amdgcn_global_load_lds(
      (const __attribute__((address_space(1))) void*)gsrc,
      (__attribute__((address_space(3))) void*)ldst, 16, 0, 0);
}

// ---------------- fused pre-pass: ONE kernel, three independent block ranges ----------------
//   b <  16384 : weight transpose+cvt (w1 -> w1t, w2 -> w2t), 64x64 tiles
//   b < 18432  : gating + inp->bf16 (atomic append to per-expert lists)
//   b < 20480  : zero y (needed because gemm2 accumulates into y with atomics)
// Node-count reduction: was 3 separate dispatches (+1 y-memset); inter-node overhead
// measured as the ~300us gap between wall time and sum of kernel durations.
__global__ __launch_bounds__(256) void fused_pre_kernel(
    const float* __restrict__ w1, const float* __restrict__ w2,
    ushort* __restrict__ w1t, ushort* __restrict__ w2t,
    const float* __restrict__ inp, const float* __restrict__ gw,
    const float* __restrict__ gb, ushort* __restrict__ inp_bf,
    int* __restrict__ counts, int* __restrict__ tok_list,
    float* __restrict__ scale_list, float* __restrict__ y) {
  __shared__ ushort tileT[64][72];   // [col][row], stride 72 (transpose part only)
  const int b = blockIdx.x;

  if (b < 16384) {
    // ---- transpose part ----
    const int which = b >> 13;         // 0 = w1, 1 = w2
    const int rem = b & 8191;
    const int e = rem >> 10;
    const int t = rem & 1023;          // 1024 tiles of 64x64 per expert-weight
    const float* src;
    ushort* dst;
    int R, C, c0, r0;
    if (which == 0) {
      src = w1 + (size_t)e * DM * DH; dst = w1t + (size_t)e * DM * DH;
      R = DM; C = DH; c0 = (t & 63) * 64; r0 = (t >> 6) * 64;
    } else {
      src = w2 + (size_t)e * DM * DH; dst = w2t + (size_t)e * DM * DH;
      R = DH; C = DM; c0 = (t & 15) * 64; r0 = (t >> 4) * 64;
    }
    const int tx = threadIdx.x & 15, ty = threadIdx.x >> 4;  // 16 x 16
#pragma unroll
    for (int i = 0; i < 4; i++) {
      int r = ty + i * 16;
      float4 v = *(const float4*)(src + (size_t)(r0 + r) * C + c0 + tx * 4);
      tileT[tx * 4 + 0][r] = f2bf(v.x);
      tileT[tx * 4 + 1][r] = f2bf(v.y);
      tileT[tx * 4 + 2][r] = f2bf(v.z);
      tileT[tx * 4 + 3][r] = f2bf(v.w);
    }
    __syncthreads();
#pragma unroll
    for (int i = 0; i < 4; i++) {
      int c = ty + i * 16;
      *(ushort4*)(dst + (size_t)(c0 + c) * R + r0 + tx * 4) = *(const ushort4*)(&tileT[c][tx * 4]);
    }
  } else if (b < 18432) {
    // ---- gating part: one wave per token ----
    const int wave = threadIdx.x >> 6, lane = threadIdx.x & 63;
    const int token = (b - 16384) * 4 + wave;
    const float* x = inp + (size_t)token * DM;
    ushort* xb = inp_bf + (size_t)token * DM;
    float acc[NE];
#pragma unroll
    for (int e = 0; e < NE; e++) acc[e] = 0.f;
#pragma unroll
    for (int j = 0; j < 16; j++) {
      int idx = j * 64 + lane;
      float xv = x[idx];
      xb[idx] = f2bf(xv);
      const float4* g = (const float4*)(gw + (size_t)idx * NE);
      float4 g0 = g[0], g1 = g[1];
      acc[0] += xv * g0.x; acc[1] += xv * g0.y; acc[2] += xv * g0.z; acc[3] += xv * g0.w;
      acc[4] += xv * g1.x; acc[5] += xv * g1.y; acc[6] += xv * g1.z; acc[7] += xv * g1.w;
    }
#pragma unroll
    for (int e = 0; e < NE; e++) {
      for (int off = 32; off; off >>= 1) acc[e] += __shfl_xor(acc[e], off, 64);
    }
    if (lane == 0) {
      float v[NE];
#pragma unroll
      for (int e = 0; e < NE; e++) v[e] = acc[e] + gb[e];
      int i0 = 0; float b0 = v[0];
#pragma unroll
      for (int e = 1; e < NE; e++) if (v[e] > b0) { b0 = v[e]; i0 = e; }
      int i1 = -1; float b1v = -INFINITY;
#pragma unroll
      for (int e = 0; e < NE; e++) if (e != i0 && v[e] > b1v) { b1v = v[e]; i1 = e; }
      float s1 = 1.f / (1.f + __expf(b0 - b1v));  // softmax over the two selected logits
      float s0 = 1.f - s1;
      int p0 = atomicAdd(&counts[i0], 1);
      tok_list[i0 * NT + p0] = token;
      scale_list[i0 * NT + p0] = s0;
      int p1 = atomicAdd(&counts[i1], 1);
      tok_list[i1 * NT + p1] = token;
      scale_list[i1 * NT + p1] = s1;
    }
  } else {
    // ---- y-zero part: 2048 blocks x 4096 floats ----
    const int idx = b - 18432;
    float4* dst = (float4*)(y + (size_t)idx * 4096);
    f32x4 z = {0.f, 0.f, 0.f, 0.f};
#pragma unroll
    for (int j = 0; j < 4; j++)
      ((f32x4*)dst)[j * 256 + threadIdx.x] = z;
  }
}

// GEMM skeleton (round-2 verified best): 128x128 tile, 256 thr (4 waves, 2x2),
// counted-vmcnt 3-buffer pipeline (T3/T4) + chunk-XOR LDS swizzle (T2, both-sides).
// Buffer = 16 KB: A[128][32]bf16 then B[128][32]bf16; within each 64B row the four
// 16B chunks sit at chunk^((row>>1)&3). 3 buffers = 48 KB.
// Each wave issues exactly 4 loads per stage -> vmcnt(4) completes the oldest stage.

#define STAGE_TILE(base)                                      \
  do {                                                        \
    async_copy16(aP0, (char*)(base) + wv * 1024);             \
    async_copy16(aP1, (char*)(base) + 4096 + wv * 1024);      \
    async_copy16(bP0, (char*)(base) + 8192 + wv * 1024);      \
    async_copy16(bP1, (char*)(base) + 12288 + wv * 1024);     \
    aP0 += 32; aP1 += 32; bP0 += 32; bP1 += 32;               \
  } while (0)

// ---------------- GEMM1: h[off_e+gi] = gelu(x[tok] @ w1[e] + b1[e]), bf16 dense ----------------
__global__ __launch_bounds__(256) void gemm1_kernel(
    const ushort* __restrict__ xbf, const ushort* __restrict__ w1t,
    const float* __restrict__ b1, const int* __restrict__ tok_list,
    const int* __restrict__ counts, ushort* __restrict__ hbuf) {
  const int b = blockIdx.x;
  const int e = b & 7;
  const int idx = b >> 3;        // 0..2047
  const int mTile = idx & 63;    // fastest
  const int nTile = idx >> 6;    // 0..31
  int off = 0;
  for (int i = 0; i < e; i++) off += counts[i];
  const int cnt = counts[e];
  if (mTile * 128 >= cnt) return;

  __shared__ __attribute__((aligned(128))) char ldsB[49152];  // 3 x (A 8KB + B 8KB)

  const int t = threadIdx.x;
  const int lane = t & 63, wv = t >> 6;
  const int wm = wv & 1, wn = wv >> 1;

  const int sr = t >> 2;                             // staging row 0..63
  const int sc = (((t & 3) ^ ((sr >> 1) & 3)) * 8);  // swizzled source chunk (ushorts)
  int gi0 = mTile * 128 + sr;      if (gi0 >= cnt) gi0 = cnt - 1;
  int gi1 = mTile * 128 + 64 + sr; if (gi1 >= cnt) gi1 = cnt - 1;
  const int tok0 = tok_list[e * NT + gi0];
  const int tok1 = tok_list[e * NT + gi1];
  const ushort* aP0 = xbf + (size_t)tok0 * DM + sc;
  const ushort* aP1 = xbf + (size_t)tok1 * DM + sc;
  const ushort* bP0 = w1t + ((size_t)e * DH + nTile * 128 + sr) * DM + sc;
  const ushort* bP1 = bP0 + (size_t)64 * DM;

  f32x4 zero = {0.f, 0.f, 0.f, 0.f};
  f32x4 acc[4][4];
#pragma unroll
  for (int i = 0; i < 4; i++)
#pragma unroll
    for (int j = 0; j < 4; j++) acc[i][j] = zero;

  const int quad = lane >> 4, lc = lane & 15;
  const int rq = quad ^ ((lc >> 1) & 3);          // swizzled chunk for reads

  auto compute = [&](const char* buf) {
    const char* A_ = buf;
    const char* B_ = buf + 8192;
    bf16x8 af[4], bfr[4];
#pragma unroll
    for (int mi = 0; mi < 4; mi++) {
      int row = wm * 64 + mi * 16 + lc;
      af[mi] = *(const bf16x8*)(A_ + row * 64 + rq * 16);
    }
#pragma unroll
    for (int ni = 0; ni < 4; ni++) {
      int row = wn * 64 + ni * 16 + lc;
      bfr[ni] = *(const bf16x8*)(B_ + row * 64 + rq * 16);
    }
#pragma unroll
    for (int mi = 0; mi < 4; mi++)
#pragma unroll
      for (int ni = 0; ni < 4; ni++)
        acc[mi][ni] = __builtin_amdgcn_mfma_f32_16x16x32_bf16(af[mi], bfr[ni], acc[mi][ni], 0, 0, 0);
  };

  const int NIT = DM / 32;  // 32
  STAGE_TILE(ldsB);
  STAGE_TILE(ldsB + 16384);
  int cur = 0;
  for (int tt = 0; tt < NIT - 1; ++tt) {
    // outstanding = stage(tt)+stage(tt+1) = 8; complete the oldest 4 = stage(tt)
    asm volatile("s_waitcnt vmcnt(4)" ::: "memory");
    __builtin_amdgcn_s_barrier();   // buf(tt) fully staged; all waves done reading buf(tt-1)
    if (tt + 2 < NIT) {
      int nx = cur + 2; if (nx >= 3) nx -= 3;
      STAGE_TILE(ldsB + nx * 16384);
    }
    compute(ldsB + cur * 16384);
    cur = (cur == 2) ? 0 : cur + 1;
  }
  asm volatile("s_waitcnt vmcnt(0)" ::: "memory");
  __builtin_amdgcn_s_barrier();
  compute(ldsB + cur * 16384);

  float bias[4];
#pragma unroll
  for (int ni = 0; ni < 4; ni++)
    bias[ni] = b1[(size_t)e * DH + nTile * 128 + wn * 64 + ni * 16 + lc];

#pragma unroll
  for (int mi = 0; mi < 4; mi++) {
#pragma unroll
    for (int r = 0; r < 4; r++) {
      int lr = wm * 64 + mi * 16 + quad * 4 + r;
      int gi = mTile * 128 + lr;
      if (gi < cnt) {
        ushort* hrow = hbuf + (size_t)(off + gi) * DH + nTile * 128 + wn * 64 + lc;
#pragma unroll
        for (int ni = 0; ni < 4; ni++) {
          float v = acc[mi][ni][r] + bias[ni];
          hrow[ni * 16] = f2bf(gelu_fast(v));
        }
      }
    }
  }
}

// ---------------- GEMM2 (fused combine): y[tok] += s * (h @ w2[e] + b2[e]) ----------------
// No split-K: each (token,expert) output row computed by exactly one block column set;
// atomics only resolve the 2-expert-per-token accumulation into y.
__global__ __launch_bounds__(256) void gemm2_kernel(
    const ushort* __restrict__ hbuf, const ushort* __restrict__ w2t,
    const float* __restrict__ b2, const int* __restrict__ tok_list,
    const float* __restrict__ scale_list, const int* __restrict__ counts,
    float* __restrict__ y) {
  const int b = blockIdx.x;
  const int e = b & 7;               // XCD pin
  const int idx = b >> 3;            // 0..511
  const int nTile = idx & 7;         // fastest: hbuf A-panel reuse
  const int mTile = idx >> 3;        // 0..63
  int off = 0;
  for (int i = 0; i < e; i++) off += counts[i];
  const int cnt = counts[e];
  if (mTile * 128 >= cnt) return;

  __shared__ __attribute__((aligned(128))) char ldsB[49152];  // 3 x (A 8KB + B 8KB)

  const int t = threadIdx.x;
  const int lane = t & 63, wv = t >> 6;
  const int wm = wv & 1, wn = wv >> 1;

  const int sr = t >> 2;
  const int sc = (((t & 3) ^ ((sr >> 1) & 3)) * 8);  // swizzled source chunk (ushorts)
  int gi0 = mTile * 128 + sr;      if (gi0 >= cnt) gi0 = cnt - 1;
  int gi1 = mTile * 128 + 64 + sr; if (gi1 >= cnt) gi1 = cnt - 1;
  const ushort* aP0 = hbuf + (size_t)(off + gi0) * DH + sc;
  const ushort* aP1 = hbuf + (size_t)(off + gi1) * DH + sc;
  const ushort* bP0 = w2t + ((size_t)e * DM + nTile * 128 + sr) * DH + sc;
  const ushort* bP1 = bP0 + (size_t)64 * DH;

  f32x4 zero = {0.f, 0.f, 0.f, 0.f};
  f32x4 acc[4][4];
#pragma unroll
  for (int i = 0; i < 4; i++)
#pragma unroll
    for (int j = 0; j < 4; j++) acc[i][j] = zero;

  const int quad = lane >> 4, lc = lane & 15;
  const int rq = quad ^ ((lc >> 1) & 3);

  auto compute = [&](const char* buf) {
    const char* A_ = buf;
    const char* B_ = buf + 8192;
    bf16x8 af[4], bfr[4];
#pragma unroll
    for (int mi = 0; mi < 4; mi++) {
      int row = wm * 64 + mi * 16 + lc;
      af[mi] = *(const bf16x8*)(A_ + row * 64 + rq * 16);
    }
#pragma unroll
    for (int ni = 0; ni < 4; ni++) {
      int row = wn * 64 + ni * 16 + lc;
      bfr[ni] = *(const bf16x8*)(B_ + row * 64 + rq * 16);
    }
#pragma unroll
    for (int mi = 0; mi < 4; mi++)
#pragma unroll
      for (int ni = 0; ni < 4; ni++)
        acc[mi][ni] = __builtin_amdgcn_mfma_f32_16x16x32_bf16(af[mi], bfr[ni], acc[mi][ni], 0, 0, 0);
  };

  const int NIT = DH / 32;  // 128
  STAGE_TILE(ldsB);
  STAGE_TILE(ldsB + 16384);
  int cur = 0;
  for (int tt = 0; tt < NIT - 1; ++tt) {
    asm volatile("s_waitcnt vmcnt(4)" ::: "memory");
    __builtin_amdgcn_s_barrier();
    if (tt + 2 < NIT) {
      int nx = cur + 2; if (nx >= 3) nx -= 3;
      STAGE_TILE(ldsB + nx * 16384);
    }
    compute(ldsB + cur * 16384);
    cur = (cur == 2) ? 0 : cur + 1;
  }
  asm volatile("s_waitcnt vmcnt(0)" ::: "memory");
  __builtin_amdgcn_s_barrier();
  compute(ldsB + cur * 16384);

  float bias[4];
#pragma unroll
  for (int ni = 0; ni < 4; ni++)
    bias[ni] = b2[(size_t)e * DM + nTile * 128 + wn * 64 + ni * 16 + lc];

#pragma unroll
  for (int mi = 0; mi < 4; mi++) {
#pragma unroll
    for (int r = 0; r < 4; r++) {
      int lr = wm * 64 + mi * 16 + quad * 4 + r;
      int gi = mTile * 128 + lr;
      if (gi < cnt) {
        int tok = tok_list[e * NT + gi];
        float s = scale_list[e * NT + gi];
        float* yrow = y + (size_t)tok * DM + nTile * 128 + wn * 64 + lc;
#pragma unroll
        for (int ni = 0; ni < 4; ni++) {
          float v = (acc[mi][ni][r] + bias[ni]) * s;
          unsafeAtomicAdd(&yrow[ni * 16], v);
        }
      }
    }
  }
}

extern "C" void kernel_launch(void* const* d_in, const int* in_sizes, int n_in,
                              void* d_out, int out_size, void* d_ws, size_t ws_size,
                              hipStream_t stream) {
  const float* inp = (const float*)d_in[0];
  const float* gw  = (const float*)d_in[1];
  const float* gb  = (const float*)d_in[2];
  const float* w1  = (const float*)d_in[3];
  const float* b1  = (const float*)d_in[4];
  const float* w2  = (const float*)d_in[5];
  const float* b2  = (const float*)d_in[6];
  float* y = (float*)d_out;

  // workspace layout (~286 MB total)
  char* ws = (char*)d_ws;
  ushort* inp_bf = (ushort*)ws;              ws += (size_t)NT * DM * 2;
  ushort* w1t    = (ushort*)ws;              ws += (size_t)NE * DH * DM * 2;
  ushort* w2t    = (ushort*)ws;              ws += (size_t)NE * DM * DH * 2;
  ushort* hbuf   = (ushort*)ws;              ws += (size_t)NP * DH * 2;
  int*    tok_list   = (int*)ws;             ws += (size_t)NE * NT * 4;
  float*  scale_list = (float*)ws;           ws += (size_t)NE * NT * 4;
  int*    counts     = (int*)ws;             ws += 256;

  hipMemsetAsync(counts, 0, 256, stream);

  // node 2: transpose (16384 blocks) + gate (2048) + y-zero (2048), fused
  fused_pre_kernel<<<20480, 256, 0, stream>>>(w1, w2, w1t, w2t, inp, gw, gb,
                                              inp_bf, counts, tok_list, scale_list, y);
  // node 3: GEMM1 (128^2, 3-buffer counted-vmcnt, swizzled — round-2 verified best)
  gemm1_kernel<<<NE * 32 * 64, 256, 0, stream>>>(inp_bf, w1t, b1, tok_list, counts, hbuf);
  // node 4: GEMM2 with fused scale+combine via atomics into y
  gemm2_kernel<<<NE * 8 * 64, 256, 0, stream>>>(hbuf, w2t, b2, tok_list, scale_list, counts, y);
}